// Round 1
// baseline (254.554 us; speedup 1.0000x reference)
//
#include <hip/hip_runtime.h>

// Octree cross-entropy loss.
// D=256, BS=16 -> 4096 level-0 blocks of 16^3 voxels.
// Level 0: per-voxel 2-class CE, mean over block, summed over blocks.
// Levels 1..4 (b = 32,64,128,256): 3-class CE (pure0/pure1/mixed) * b^3,
// class derived from per-16^3-block popcounts of gt01 aggregated upward.

__device__ __forceinline__ float nll2(float l0, float l1, int t) {
    float m = fmaxf(l0, l1);
    float lse = m + __logf(__expf(l0 - m) + __expf(l1 - m));
    return lse - (t ? l1 : l0);
}

__device__ __forceinline__ float nll3(const float* __restrict__ l, int c) {
    float a = l[0], b = l[1], d = l[2];
    float m = fmaxf(fmaxf(a, b), d);
    float lse = m + __logf(__expf(a - m) + __expf(b - m) + __expf(d - m));
    return lse - l[c];
}

// One thread block per 16^3 octree block. 256 threads, 16 voxels/thread
// via 4 x (int4 gt + 2x float4 logits) vector loads.
__global__ __launch_bounds__(256) void level0_kernel(
    const int* __restrict__ gt,        // [256^3], values +-1, x-major (x,y,z)
    const float* __restrict__ logits,  // [4096, 2, 4096]
    float* __restrict__ out,           // [1], pre-zeroed
    int* __restrict__ ones_count)      // [4096] per-block popcount of gt01
{
    const int blk = blockIdx.x;              // (bx*16 + by)*16 + bz
    const int tid = threadIdx.x;
    const int bx = blk >> 8;
    const int by = (blk >> 4) & 15;
    const int bz = blk & 15;

    const float* lg0 = logits + (size_t)blk * 8192;
    const float* lg1 = lg0 + 4096;

    float lsum = 0.f;
    int ones = 0;

#pragma unroll
    for (int it = 0; it < 4; ++it) {
        const int v4 = tid + it * 256;       // float4 chunk index 0..1023
        const int v  = v4 << 2;              // voxel index (ix*16+iy)*16+iz
        const int ix = v >> 8;
        const int iy = (v >> 4) & 15;
        const int iz = v & 15;               // 0,4,8,12 -> 4 consecutive z
        const size_t gidx =
            ((size_t)(bx * 16 + ix) * 256 + (size_t)(by * 16 + iy)) * 256
            + (size_t)(bz * 16 + iz);
        const int4   g = *reinterpret_cast<const int4*>(gt + gidx);
        const float4 a = *reinterpret_cast<const float4*>(lg0 + v);
        const float4 b = *reinterpret_cast<const float4*>(lg1 + v);
        const int t0 = g.x > 0, t1 = g.y > 0, t2 = g.z > 0, t3 = g.w > 0;
        ones += t0 + t1 + t2 + t3;
        lsum += nll2(a.x, b.x, t0);
        lsum += nll2(a.y, b.y, t1);
        lsum += nll2(a.z, b.z, t2);
        lsum += nll2(a.w, b.w, t3);
    }

    __shared__ float sf[256];
    __shared__ int   si[256];
    sf[tid] = lsum;
    si[tid] = ones;
    __syncthreads();
#pragma unroll
    for (int s = 128; s > 0; s >>= 1) {
        if (tid < s) { sf[tid] += sf[tid + s]; si[tid] += si[tid + s]; }
        __syncthreads();
    }
    if (tid == 0) {
        atomicAdd(out, sf[0] * (1.0f / 4096.0f));  // mean over 16^3 voxels
        ones_count[blk] = si[0];
    }
}

// Single block, 512 threads: hierarchical aggregation of popcounts and
// 3-class CE for levels 1..4.
__global__ __launch_bounds__(512) void levels_kernel(
    const int* __restrict__ cnt0,   // [4096] ordered (bx*16+by)*16+bz
    const float* __restrict__ l1,   // [512,3]
    const float* __restrict__ l2,   // [64,3]
    const float* __restrict__ l3,   // [8,3]
    const float* __restrict__ l4,   // [1,3]
    float* __restrict__ out)
{
    __shared__ int   s1[512];
    __shared__ int   s2[64];
    __shared__ int   s3[8];
    __shared__ float red[512];
    const int tid = threadIdx.x;
    float contrib = 0.f;

    // level 1: 8^3 blocks, each aggregates 2^3 level-0 blocks (16^3 grid)
    {
        const int X = tid >> 6, Y = (tid >> 3) & 7, Z = tid & 7;
        int s = 0;
#pragma unroll
        for (int dx = 0; dx < 2; ++dx)
#pragma unroll
            for (int dy = 0; dy < 2; ++dy)
#pragma unroll
                for (int dz = 0; dz < 2; ++dz)
                    s += cnt0[((X * 2 + dx) * 16 + (Y * 2 + dy)) * 16 + (Z * 2 + dz)];
        s1[tid] = s;
        const int tot = 8 * 4096;
        const int c = (s == 0) ? 0 : ((s == tot) ? 1 : 2);
        contrib += nll3(l1 + tid * 3, c) * 32768.0f;      // 32^3
    }
    __syncthreads();
    // level 2: 4^3 blocks from 8^3 grid
    if (tid < 64) {
        const int X = tid >> 4, Y = (tid >> 2) & 3, Z = tid & 3;
        int s = 0;
#pragma unroll
        for (int dx = 0; dx < 2; ++dx)
#pragma unroll
            for (int dy = 0; dy < 2; ++dy)
#pragma unroll
                for (int dz = 0; dz < 2; ++dz)
                    s += s1[((X * 2 + dx) * 8 + (Y * 2 + dy)) * 8 + (Z * 2 + dz)];
        s2[tid] = s;
        const int tot = 64 * 4096;
        const int c = (s == 0) ? 0 : ((s == tot) ? 1 : 2);
        contrib += nll3(l2 + tid * 3, c) * 262144.0f;     // 64^3
    }
    __syncthreads();
    // level 3: 2^3 blocks from 4^3 grid
    if (tid < 8) {
        const int X = tid >> 2, Y = (tid >> 1) & 1, Z = tid & 1;
        int s = 0;
#pragma unroll
        for (int dx = 0; dx < 2; ++dx)
#pragma unroll
            for (int dy = 0; dy < 2; ++dy)
#pragma unroll
                for (int dz = 0; dz < 2; ++dz)
                    s += s2[((X * 2 + dx) * 4 + (Y * 2 + dy)) * 4 + (Z * 2 + dz)];
        s3[tid] = s;
        const int tot = 512 * 4096;
        const int c = (s == 0) ? 0 : ((s == tot) ? 1 : 2);
        contrib += nll3(l3 + tid * 3, c) * 2097152.0f;    // 128^3
    }
    __syncthreads();
    // level 4: 1 block = everything
    if (tid == 0) {
        int s = 0;
#pragma unroll
        for (int i = 0; i < 8; ++i) s += s3[i];
        const int tot = 4096 * 4096;
        const int c = (s == 0) ? 0 : ((s == tot) ? 1 : 2);
        contrib += nll3(l4, c) * 16777216.0f;             // 256^3
    }

    red[tid] = contrib;
    __syncthreads();
#pragma unroll
    for (int s = 256; s > 0; s >>= 1) {
        if (tid < s) red[tid] += red[tid + s];
        __syncthreads();
    }
    if (tid == 0) atomicAdd(out, red[0]);
}

extern "C" void kernel_launch(void* const* d_in, const int* in_sizes, int n_in,
                              void* d_out, int out_size, void* d_ws, size_t ws_size,
                              hipStream_t stream) {
    const int*   gt    = (const int*)d_in[0];
    const float* dense = (const float*)d_in[1];
    const float* l1    = (const float*)d_in[2];
    const float* l2    = (const float*)d_in[3];
    const float* l3    = (const float*)d_in[4];
    const float* l4    = (const float*)d_in[5];
    float* out = (float*)d_out;
    int*   cnt = (int*)d_ws;   // 4096 ints

    hipMemsetAsync(out, 0, sizeof(float), stream);
    level0_kernel<<<4096, 256, 0, stream>>>(gt, dense, out, cnt);
    levels_kernel<<<1, 512, 0, stream>>>(cnt, l1, l2, l3, l4, out);
}

// Round 2
// 247.589 us; speedup vs baseline: 1.0281x; 1.0281x over previous
//
#include <hip/hip_runtime.h>

// Octree cross-entropy loss.
// D=256, BS=16 -> 4096 level-0 blocks of 16^3 voxels.
// Level 0: per-voxel 2-class CE, mean over block, summed over blocks.
// Levels 1..4 (b = 32,64,128,256): 3-class CE (pure0/pure1/mixed) * b^3,
// class derived from per-16^3-block popcounts of gt01 aggregated upward.
//
// R1 -> R2 changes:
//  - All 12 vector loads per thread batched (addresses, then loads, then
//    compute) to get 12 outstanding requests/wave instead of ~1 (R1 had
//    VGPR=24 => compiler serialized loads; latency-bound at 2.36 TB/s).
//  - 2-class NLL as softplus(+-(l0-l1)): 1 exp + 1 log per voxel.
//  - No same-address atomics: per-block partials in d_ws, reduced by the
//    tiny second kernel, which writes out[0] once (no memset needed).

__device__ __forceinline__ float softplus(float x) {
    // log(1 + e^x), stable
    return fmaxf(x, 0.f) + __logf(1.f + __expf(-fabsf(x)));
}

__device__ __forceinline__ float nll3(const float* __restrict__ l, int c) {
    float a = l[0], b = l[1], d = l[2];
    float m = fmaxf(fmaxf(a, b), d);
    float lse = m + __logf(__expf(a - m) + __expf(b - m) + __expf(d - m));
    return lse - l[c];
}

// One thread block per 16^3 octree block. 256 threads, 16 voxels/thread.
__global__ __launch_bounds__(256) void level0_kernel(
    const int* __restrict__ gt,        // [256^3], values +-1, x-major (x,y,z)
    const float* __restrict__ logits,  // [4096, 2, 4096]
    float* __restrict__ partial,       // [4096] per-block mean NLL
    int* __restrict__ ones_count)      // [4096] per-block popcount of gt01
{
    const int blk = blockIdx.x;              // (bx*16 + by)*16 + bz
    const int tid = threadIdx.x;
    const int bx = blk >> 8;
    const int by = (blk >> 4) & 15;
    const int bz = blk & 15;

    const float* lg0 = logits + (size_t)blk * 8192;
    const float* lg1 = lg0 + 4096;

    // ---- issue ALL loads before any use ----
    int4   g[4];
    float4 a[4], b[4];
#pragma unroll
    for (int it = 0; it < 4; ++it) {
        const int v  = (tid + it * 256) << 2;    // voxel idx (ix*16+iy)*16+iz
        const int ix = v >> 8;
        const int iy = (v >> 4) & 15;
        const int iz = v & 15;
        const int gidx = ((bx * 16 + ix) << 16) + ((by * 16 + iy) << 8)
                       + (bz * 16 + iz);
        g[it] = *reinterpret_cast<const int4*>(gt + gidx);
    }
#pragma unroll
    for (int it = 0; it < 4; ++it) {
        const int v = (tid + it * 256) << 2;
        a[it] = *reinterpret_cast<const float4*>(lg0 + v);
    }
#pragma unroll
    for (int it = 0; it < 4; ++it) {
        const int v = (tid + it * 256) << 2;
        b[it] = *reinterpret_cast<const float4*>(lg1 + v);
    }

    // ---- compute ----
    float lsum = 0.f;
    int ones = 0;
#pragma unroll
    for (int it = 0; it < 4; ++it) {
        const float dx = a[it].x - b[it].x;
        const float dy = a[it].y - b[it].y;
        const float dz = a[it].z - b[it].z;
        const float dw = a[it].w - b[it].w;
        const int t0 = g[it].x > 0, t1 = g[it].y > 0;
        const int t2 = g[it].z > 0, t3 = g[it].w > 0;
        ones += t0 + t1 + t2 + t3;
        // target=1 -> nll = softplus(l0-l1) = softplus(d); target=0 -> softplus(-d)
        lsum += softplus(t0 ? dx : -dx);
        lsum += softplus(t1 ? dy : -dy);
        lsum += softplus(t2 ? dz : -dz);
        lsum += softplus(t3 ? dw : -dw);
    }

    // ---- wave reduce, then cross-wave via LDS ----
#pragma unroll
    for (int s = 32; s > 0; s >>= 1) {
        lsum += __shfl_down(lsum, s, 64);
        ones += __shfl_down(ones, s, 64);
    }
    __shared__ float sf[4];
    __shared__ int   si[4];
    const int wave = tid >> 6;
    if ((tid & 63) == 0) { sf[wave] = lsum; si[wave] = ones; }
    __syncthreads();
    if (tid == 0) {
        partial[blk] = (sf[0] + sf[1] + sf[2] + sf[3]) * (1.0f / 4096.0f);
        ones_count[blk] = si[0] + si[1] + si[2] + si[3];
    }
}

// Single block, 512 threads: reduce level-0 partials, hierarchical popcount
// aggregation, 3-class CE for levels 1..4, write final out[0].
__global__ __launch_bounds__(512) void levels_kernel(
    const float* __restrict__ partial, // [4096]
    const int* __restrict__ cnt0,      // [4096] ordered (bx*16+by)*16+bz
    const float* __restrict__ l1,      // [512,3]
    const float* __restrict__ l2,      // [64,3]
    const float* __restrict__ l3,      // [8,3]
    const float* __restrict__ l4,      // [1,3]
    float* __restrict__ out)
{
    __shared__ int   s1[512];
    __shared__ int   s2[64];
    __shared__ int   s3[8];
    __shared__ float red[512];
    const int tid = threadIdx.x;
    float contrib = 0.f;

    // level-0 partial losses: 8 floats per thread
    {
        const float4 p0 = *reinterpret_cast<const float4*>(partial + tid * 8);
        const float4 p1 = *reinterpret_cast<const float4*>(partial + tid * 8 + 4);
        contrib += (p0.x + p0.y + p0.z + p0.w) + (p1.x + p1.y + p1.z + p1.w);
    }

    // level 1: 8^3 blocks, each aggregates 2^3 level-0 blocks (16^3 grid)
    {
        const int X = tid >> 6, Y = (tid >> 3) & 7, Z = tid & 7;
        int s = 0;
#pragma unroll
        for (int dx = 0; dx < 2; ++dx)
#pragma unroll
            for (int dy = 0; dy < 2; ++dy)
#pragma unroll
                for (int dz = 0; dz < 2; ++dz)
                    s += cnt0[((X * 2 + dx) * 16 + (Y * 2 + dy)) * 16 + (Z * 2 + dz)];
        s1[tid] = s;
        const int tot = 8 * 4096;
        const int c = (s == 0) ? 0 : ((s == tot) ? 1 : 2);
        contrib += nll3(l1 + tid * 3, c) * 32768.0f;      // 32^3
    }
    __syncthreads();
    // level 2: 4^3 blocks from 8^3 grid
    if (tid < 64) {
        const int X = tid >> 4, Y = (tid >> 2) & 3, Z = tid & 3;
        int s = 0;
#pragma unroll
        for (int dx = 0; dx < 2; ++dx)
#pragma unroll
            for (int dy = 0; dy < 2; ++dy)
#pragma unroll
                for (int dz = 0; dz < 2; ++dz)
                    s += s1[((X * 2 + dx) * 8 + (Y * 2 + dy)) * 8 + (Z * 2 + dz)];
        s2[tid] = s;
        const int tot = 64 * 4096;
        const int c = (s == 0) ? 0 : ((s == tot) ? 1 : 2);
        contrib += nll3(l2 + tid * 3, c) * 262144.0f;     // 64^3
    }
    __syncthreads();
    // level 3: 2^3 blocks from 4^3 grid
    if (tid < 8) {
        const int X = tid >> 2, Y = (tid >> 1) & 1, Z = tid & 1;
        int s = 0;
#pragma unroll
        for (int dx = 0; dx < 2; ++dx)
#pragma unroll
            for (int dy = 0; dy < 2; ++dy)
#pragma unroll
                for (int dz = 0; dz < 2; ++dz)
                    s += s2[((X * 2 + dx) * 4 + (Y * 2 + dy)) * 4 + (Z * 2 + dz)];
        s3[tid] = s;
        const int tot = 512 * 4096;
        const int c = (s == 0) ? 0 : ((s == tot) ? 1 : 2);
        contrib += nll3(l3 + tid * 3, c) * 2097152.0f;    // 128^3
    }
    __syncthreads();
    // level 4: 1 block = everything
    if (tid == 0) {
        int s = 0;
#pragma unroll
        for (int i = 0; i < 8; ++i) s += s3[i];
        const int tot = 4096 * 4096;
        const int c = (s == 0) ? 0 : ((s == tot) ? 1 : 2);
        contrib += nll3(l4, c) * 16777216.0f;             // 256^3
    }

    red[tid] = contrib;
    __syncthreads();
#pragma unroll
    for (int s = 256; s > 0; s >>= 1) {
        if (tid < s) red[tid] += red[tid + s];
        __syncthreads();
    }
    if (tid == 0) out[0] = red[0];
}

extern "C" void kernel_launch(void* const* d_in, const int* in_sizes, int n_in,
                              void* d_out, int out_size, void* d_ws, size_t ws_size,
                              hipStream_t stream) {
    const int*   gt    = (const int*)d_in[0];
    const float* dense = (const float*)d_in[1];
    const float* l1    = (const float*)d_in[2];
    const float* l2    = (const float*)d_in[3];
    const float* l3    = (const float*)d_in[4];
    const float* l4    = (const float*)d_in[5];
    float* out = (float*)d_out;

    float* partial = (float*)d_ws;            // 4096 floats
    int*   cnt     = (int*)(partial + 4096);  // 4096 ints

    level0_kernel<<<4096, 256, 0, stream>>>(gt, dense, partial, cnt);
    levels_kernel<<<1, 512, 0, stream>>>(partial, cnt, l1, l2, l3, l4, out);
}

// Round 3
// 244.381 us; speedup vs baseline: 1.0416x; 1.0131x over previous
//
#include <hip/hip_runtime.h>

// Octree cross-entropy loss.
// D=256, BS=16 -> 4096 level-0 blocks of 16^3 voxels.
// Level 0: per-voxel 2-class CE, mean over block, summed over blocks.
// Levels 1..4 (b = 32,64,128,256): 3-class CE (pure0/pure1/mixed) * b^3,
// class derived from per-16^3-block popcounts of gt01 aggregated upward.
//
// R2 -> R3 changes:
//  - level0: 1024-thread blocks, 4 voxels/thread (exactly 3 vector loads:
//    int4 gt + 2x float4 logits). R2 showed the compiler caps VGPR at 32 and
//    serializes >2 outstanding loads per wave; instead of ILP-per-wave we get
//    MLP from wave count: 16 waves/block, 2 blocks/CU = 100% occupancy,
//    ~96 KB in flight per CU vs ~9 KB needed for 6.3 TB/s.

__device__ __forceinline__ float softplus(float x) {
    // log(1 + e^x), stable
    return fmaxf(x, 0.f) + __logf(1.f + __expf(-fabsf(x)));
}

__device__ __forceinline__ float nll3(const float* __restrict__ l, int c) {
    float a = l[0], b = l[1], d = l[2];
    float m = fmaxf(fmaxf(a, b), d);
    float lse = m + __logf(__expf(a - m) + __expf(b - m) + __expf(d - m));
    return lse - l[c];
}

// One thread block per 16^3 octree block. 1024 threads, 4 voxels/thread.
__global__ __launch_bounds__(1024) void level0_kernel(
    const int* __restrict__ gt,        // [256^3], values +-1, x-major (x,y,z)
    const float* __restrict__ logits,  // [4096, 2, 4096]
    float* __restrict__ partial,       // [4096] per-block mean NLL
    int* __restrict__ ones_count)      // [4096] per-block popcount of gt01
{
    const int blk = blockIdx.x;              // (bx*16 + by)*16 + bz
    const int tid = threadIdx.x;
    const int bx = blk >> 8;
    const int by = (blk >> 4) & 15;
    const int bz = blk & 15;

    const float* lg0 = logits + (size_t)blk * 8192;
    const float* lg1 = lg0 + 4096;

    const int v  = tid << 2;                 // voxel idx (ix*16+iy)*16+iz
    const int ix = v >> 8;
    const int iy = (v >> 4) & 15;
    const int iz = v & 15;
    const int gidx = ((bx * 16 + ix) << 16) + ((by * 16 + iy) << 8)
                   + (bz * 16 + iz);

    const int4   g = *reinterpret_cast<const int4*>(gt + gidx);
    const float4 a = *reinterpret_cast<const float4*>(lg0 + v);
    const float4 b = *reinterpret_cast<const float4*>(lg1 + v);

    const float dx = a.x - b.x;
    const float dy = a.y - b.y;
    const float dz = a.z - b.z;
    const float dw = a.w - b.w;
    const int t0 = g.x > 0, t1 = g.y > 0, t2 = g.z > 0, t3 = g.w > 0;
    int   ones = t0 + t1 + t2 + t3;
    // target=1 -> nll = softplus(l0-l1); target=0 -> softplus(-(l0-l1))
    float lsum = softplus(t0 ? dx : -dx)
               + softplus(t1 ? dy : -dy)
               + softplus(t2 ? dz : -dz)
               + softplus(t3 ? dw : -dw);

    // ---- wave reduce, then cross-wave via LDS ----
#pragma unroll
    for (int s = 32; s > 0; s >>= 1) {
        lsum += __shfl_down(lsum, s, 64);
        ones += __shfl_down(ones, s, 64);
    }
    __shared__ float sf[16];
    __shared__ int   si[16];
    const int wave = tid >> 6;
    if ((tid & 63) == 0) { sf[wave] = lsum; si[wave] = ones; }
    __syncthreads();
    if (tid == 0) {
        float fs = 0.f;
        int   is = 0;
#pragma unroll
        for (int i = 0; i < 16; ++i) { fs += sf[i]; is += si[i]; }
        partial[blk] = fs * (1.0f / 4096.0f);   // mean over 16^3 voxels
        ones_count[blk] = is;
    }
}

// Single block, 512 threads: reduce level-0 partials, hierarchical popcount
// aggregation, 3-class CE for levels 1..4, write final out[0].
__global__ __launch_bounds__(512) void levels_kernel(
    const float* __restrict__ partial, // [4096]
    const int* __restrict__ cnt0,      // [4096] ordered (bx*16+by)*16+bz
    const float* __restrict__ l1,      // [512,3]
    const float* __restrict__ l2,      // [64,3]
    const float* __restrict__ l3,      // [8,3]
    const float* __restrict__ l4,      // [1,3]
    float* __restrict__ out)
{
    __shared__ int   s1[512];
    __shared__ int   s2[64];
    __shared__ int   s3[8];
    __shared__ float red[512];
    const int tid = threadIdx.x;
    float contrib = 0.f;

    // level-0 partial losses: 8 floats per thread
    {
        const float4 p0 = *reinterpret_cast<const float4*>(partial + tid * 8);
        const float4 p1 = *reinterpret_cast<const float4*>(partial + tid * 8 + 4);
        contrib += (p0.x + p0.y + p0.z + p0.w) + (p1.x + p1.y + p1.z + p1.w);
    }

    // level 1: 8^3 blocks, each aggregates 2^3 level-0 blocks (16^3 grid)
    {
        const int X = tid >> 6, Y = (tid >> 3) & 7, Z = tid & 7;
        int s = 0;
#pragma unroll
        for (int dx = 0; dx < 2; ++dx)
#pragma unroll
            for (int dy = 0; dy < 2; ++dy)
#pragma unroll
                for (int dz = 0; dz < 2; ++dz)
                    s += cnt0[((X * 2 + dx) * 16 + (Y * 2 + dy)) * 16 + (Z * 2 + dz)];
        s1[tid] = s;
        const int tot = 8 * 4096;
        const int c = (s == 0) ? 0 : ((s == tot) ? 1 : 2);
        contrib += nll3(l1 + tid * 3, c) * 32768.0f;      // 32^3
    }
    __syncthreads();
    // level 2: 4^3 blocks from 8^3 grid
    if (tid < 64) {
        const int X = tid >> 4, Y = (tid >> 2) & 3, Z = tid & 3;
        int s = 0;
#pragma unroll
        for (int dx = 0; dx < 2; ++dx)
#pragma unroll
            for (int dy = 0; dy < 2; ++dy)
#pragma unroll
                for (int dz = 0; dz < 2; ++dz)
                    s += s1[((X * 2 + dx) * 8 + (Y * 2 + dy)) * 8 + (Z * 2 + dz)];
        s2[tid] = s;
        const int tot = 64 * 4096;
        const int c = (s == 0) ? 0 : ((s == tot) ? 1 : 2);
        contrib += nll3(l2 + tid * 3, c) * 262144.0f;     // 64^3
    }
    __syncthreads();
    // level 3: 2^3 blocks from 4^3 grid
    if (tid < 8) {
        const int X = tid >> 2, Y = (tid >> 1) & 1, Z = tid & 1;
        int s = 0;
#pragma unroll
        for (int dx = 0; dx < 2; ++dx)
#pragma unroll
            for (int dy = 0; dy < 2; ++dy)
#pragma unroll
                for (int dz = 0; dz < 2; ++dz)
                    s += s2[((X * 2 + dx) * 4 + (Y * 2 + dy)) * 4 + (Z * 2 + dz)];
        s3[tid] = s;
        const int tot = 512 * 4096;
        const int c = (s == 0) ? 0 : ((s == tot) ? 1 : 2);
        contrib += nll3(l3 + tid * 3, c) * 2097152.0f;    // 128^3
    }
    __syncthreads();
    // level 4: 1 block = everything
    if (tid == 0) {
        int s = 0;
#pragma unroll
        for (int i = 0; i < 8; ++i) s += s3[i];
        const int tot = 4096 * 4096;
        const int c = (s == 0) ? 0 : ((s == tot) ? 1 : 2);
        contrib += nll3(l4, c) * 16777216.0f;             // 256^3
    }

    red[tid] = contrib;
    __syncthreads();
#pragma unroll
    for (int s = 256; s > 0; s >>= 1) {
        if (tid < s) red[tid] += red[tid + s];
        __syncthreads();
    }
    if (tid == 0) out[0] = red[0];
}

extern "C" void kernel_launch(void* const* d_in, const int* in_sizes, int n_in,
                              void* d_out, int out_size, void* d_ws, size_t ws_size,
                              hipStream_t stream) {
    const int*   gt    = (const int*)d_in[0];
    const float* dense = (const float*)d_in[1];
    const float* l1    = (const float*)d_in[2];
    const float* l2    = (const float*)d_in[3];
    const float* l3    = (const float*)d_in[4];
    const float* l4    = (const float*)d_in[5];
    float* out = (float*)d_out;

    float* partial = (float*)d_ws;            // 4096 floats
    int*   cnt     = (int*)(partial + 4096);  // 4096 ints

    level0_kernel<<<4096, 1024, 0, stream>>>(gt, dense, partial, cnt);
    levels_kernel<<<1, 512, 0, stream>>>(partial, cnt, l1, l2, l3, l4, out);
}